// Round 12
// baseline (756.902 us; speedup 1.0000x reference)
//
#include <hip/hip_runtime.h>
#include <math.h>

#define NS 150
#define LDW 152
#define NPACK 11848   // packed upper-tri floats (rows 16B-aligned)
#define NT 40
#define MS 200
#define MT 30
#define N_SWEEPS 6
#define ROUNDS (N_SWEEPS*(NT-1))
#define JITTER 0.1f

// packed upper-tri storage: row r holds cols [r&~3, 152), 16B-aligned start.
// valid for r in [0,150]; rs_off(150) == NPACK.
__device__ __forceinline__ int rs_off(int r) {
    int g = r >> 2, rm = r & 3;
    return LDW * r - 8 * g * (g - 1) - 4 * rm * g;
}

__device__ __forceinline__ void jac_params(const float (*A)[NT+1], float4* dst,
                                           int i, int rr) {
    int i0 = i, i1 = NT - 1 - i;
    int p = (i0 == 0) ? 0 : ((i0 - 1 + rr) % (NT - 1)) + 1;
    int q = ((i1 - 1 + rr) % (NT - 1)) + 1;
    if (p > q) { int tsw = p; p = q; q = tsw; }
    float app = A[p][p], aqq = A[q][q], apq = A[p][q];
    float c, s;
    if (apq == 0.0f) { c = 1.0f; s = 0.0f; }
    else {
        float tau = (aqq - app) / (2.0f * apq);
        float tt = ((tau >= 0.0f) ? 1.0f : -1.0f) / (fabsf(tau) + sqrtf(1.0f + tau*tau));
        c = rsqrtf(1.0f + tt*tt);
        s = tt * c;
    }
    dst[i] = make_float4(c, s, __int_as_float(p), __int_as_float(q));
}

// K1: 1 block, 256 threads. T built in LDS; cyclic Jacobi with ONE barrier per
//     round: per-wave redundant params (wave_barrier only), A double-buffered
//     (read cur, write nxt — disjoint 2x2 write tiles), V in-place (disjoint
//     2x4 regions). Tail: wt, G = V^T stData^T, Amat = Tt*V (f4 dots).
//     NOTE (R11 post-mortem): output absmax is Jacobi-CONVERGENCE-limited:
//     10 sweeps->0.0039, 8->0.0078, 6->0.0117, 5->0.0508 (fails). Keep 6.
__global__ void __launch_bounds__(256) jacobi_all(
        const float* __restrict__ tc, const float* __restrict__ ttc,
        const float* __restrict__ st, const float* __restrict__ llt,
        float* __restrict__ wt, float* __restrict__ G, float* __restrict__ Amat) {
    __shared__ __align__(16) float A2[2][NT][NT + 1];
    __shared__ __align__(16) float Vts[NT][44];     // Vts[j][k] = V[k][j]
    __shared__ __align__(16) float4 prm[4][NT/2];   // per-wave param scratch
    __shared__ float tcs[NT];
    __shared__ __align__(16) float sts[NS*NT];
    __shared__ float Tts[MT*NT];
    int tid = threadIdx.x;
    float ilt2 = expf(-2.0f * llt[0]);
    if (tid < NT) tcs[tid] = tc[tid];
    for (int t4 = tid * 4; t4 < NS*NT; t4 += 1024)
        *(float4*)&sts[t4] = *(const float4*)&st[t4];
    __syncthreads();
    for (int idx = tid; idx < NT*NT; idx += 256) {
        int i = idx / NT, jj = idx - i*NT;
        float dt = tcs[i] - tcs[jj];
        float v = expf(-dt*dt*ilt2);
        if (i == jj) v += JITTER;
        A2[0][i][jj] = v;
    }
    for (int idx = tid; idx < NT*44; idx += 256) {
        int jr = idx / 44, k = idx - jr*44;
        Vts[jr][k] = (jr == k) ? 1.0f : 0.0f;
    }
    __syncthreads();
    int wave = tid >> 6, lane = tid & 63;
    for (int rd = 0; rd < ROUNDS; ++rd) {
        int cur = rd & 1, nxt = cur ^ 1;
        float4* wp = prm[wave];
        if (lane < NT/2) jac_params(A2[cur], wp, lane, rd % (NT - 1));
        __builtin_amdgcn_wave_barrier();   // pin compiler order; same-wave LDS is in-order
        for (int t = tid; t < 600; t += 256) {
            if (t < 400) {
                int bi = t / 20, bj = t - bi*20;
                float4 Pi = wp[bi], Pj = wp[bj];
                int pi = __float_as_int(Pi.z), qi = __float_as_int(Pi.w);
                int pj = __float_as_int(Pj.z), qj = __float_as_int(Pj.w);
                float ci = Pi.x, si = Pi.y, cj = Pj.x, sj = Pj.y;
                float a00 = A2[cur][pi][pj], a01 = A2[cur][pi][qj];
                float a10 = A2[cur][qi][pj], a11 = A2[cur][qi][qj];
                float b00 = ci*a00 - si*a10, b01 = ci*a01 - si*a11;
                float b10 = si*a00 + ci*a10, b11 = si*a01 + ci*a11;
                A2[nxt][pi][pj] = cj*b00 - sj*b01; A2[nxt][pi][qj] = sj*b00 + cj*b01;
                A2[nxt][qi][pj] = cj*b10 - sj*b11; A2[nxt][qi][qj] = sj*b10 + cj*b11;
            } else {
                int u2 = t - 400;
                int pr = u2 / 10, ch = (u2 - pr*10) << 2;
                float4 P = wp[pr];
                int pj = __float_as_int(P.z), qj = __float_as_int(P.w);
                float c = P.x, s = P.y;
                float4 vp = *(float4*)&Vts[pj][ch];
                float4 vq = *(float4*)&Vts[qj][ch];
                float4 np, nq;
                np.x = c*vp.x - s*vq.x; nq.x = s*vp.x + c*vq.x;
                np.y = c*vp.y - s*vq.y; nq.y = s*vp.y + c*vq.y;
                np.z = c*vp.z - s*vq.z; nq.z = s*vp.z + c*vq.z;
                np.w = c*vp.w - s*vq.w; nq.w = s*vp.w + c*vq.w;
                *(float4*)&Vts[pj][ch] = np;
                *(float4*)&Vts[qj][ch] = nq;
            }
        }
        __syncthreads();
    }
    const int fin = ROUNDS & 1;
    if (tid < NT) wt[tid] = A2[fin][tid][tid];
    for (int idx = tid; idx < NT*NS; idx += 256) {
        int jj = idx / NS, r = idx - jj*NS;
        const float4* va = (const float4*)&Vts[jj][0];
        const float4* sa = (const float4*)&sts[r*NT];
        float acc = 0.0f;
        #pragma unroll
        for (int c4 = 0; c4 < NT/4; ++c4) {
            float4 a = va[c4], b = sa[c4];
            acc += a.x*b.x + a.y*b.y + a.z*b.z + a.w*b.w;
        }
        G[idx] = acc;
    }
    for (int idx = tid; idx < MT*NT; idx += 256) {
        int it = idx / NT, t2 = idx - it*NT;
        float dt = ttc[it] - tcs[t2];
        Tts[idx] = expf(-dt*dt*ilt2);
    }
    __syncthreads();
    for (int idx = tid; idx < MT*NT; idx += 256) {
        int it = idx / NT, jj = idx - it*NT;
        const float4* ta = (const float4*)&Tts[it*NT];
        const float4* va = (const float4*)&Vts[jj][0];
        float s = 0.0f;
        #pragma unroll
        for (int c4 = 0; c4 < NT/4; ++c4) {
            float4 a = ta[c4], b = va[c4];
            s += a.x*b.x + a.y*b.y + a.z*b.z + a.w*b.w;
        }
        Amat[idx] = s;
    }
}

// K2: 40 blocks. M_j = wtj*(S + JITTER*I) + nv*I built from coords into packed
//     LDS (RHS g as col 150); rank-4 panels with pre-eliminated panel rows
//     (phase A) and full-occupancy packed-chunk trailing update (phase B, u8
//     rowOf table); in-LDS scaling; fused trsm over 200 test columns.
__global__ void __launch_bounds__(256, 1) chol_solve_all(
        const float* __restrict__ sc, const float* __restrict__ tsc,
        const float* __restrict__ lll, const float* __restrict__ lle,
        const float* __restrict__ lnv, const float* __restrict__ wtg,
        const float* __restrict__ G, float* __restrict__ q, float* __restrict__ R) {
    __shared__ __align__(16) float Mp[NPACK];
    __shared__ __align__(16) float Pr[4][LDW];
    __shared__ uint8_t rowOf[(NPACK/4) + 2];
    __shared__ float invs[4];
    __shared__ float dvs[NS];
    __shared__ float scs[NS*3];
    __shared__ float tscs[MS*3];
    int j = blockIdx.x, tid = threadIdx.x;
    float wtj = wtg[j];
    float nv = expf(lnv[0]);
    float ill2 = expf(-2.0f * lll[0]);
    float ile2 = expf(-2.0f * lle[0]);
    for (int t = tid; t < NS*3; t += 256) scs[t] = sc[t];
    for (int t = tid; t < MS*3; t += 256) tscs[t] = tsc[t];
    if (tid < NS) {
        int r = tid;
        int b0 = rs_off(r) >> 2, b1 = rs_off(r+1) >> 2;
        for (int pk = b0; pk < b1; ++pk) rowOf[pk] = (uint8_t)r;
    }
    __syncthreads();
    for (int idx = tid; idx < NS*LDW; idx += 256) {
        int r = idx / LDW, c = idx - r*LDW;
        int rbase = r & ~3;
        if (c < rbase) continue;
        float v;
        if (c < NS) {
            float d0 = scs[r*3+0] - scs[c*3+0];
            float d1 = scs[r*3+1] - scs[c*3+1];
            float d2 = scs[r*3+2] - scs[c*3+2];
            v = wtj * expf(-((d0*d0 + d1*d1)*ill2 + d2*d2*ile2));
            if (c == r) v += wtj * JITTER + nv;   // spatial jitter rides wtj
        } else if (c == NS) {
            v = G[j*NS + r];
        } else {
            v = 0.0f;
        }
        Mp[rs_off(r) + c - rbase] = v;
    }
    __syncthreads();
    for (int k0 = 0; k0 < NS - 1; k0 += 4) {
        int P = NS - k0; if (P > 4) P = 4;
        int W4 = (LDW - k0) >> 2;
        // phase A: stage + pre-eliminate panel rows into Pr (single wave)
        if (tid < W4) {
            int o0 = rs_off(k0);
            int o1 = (P > 1) ? rs_off(k0+1) : o0;
            int o2 = (P > 2) ? rs_off(k0+2) : o0;
            int o3 = (P > 3) ? rs_off(k0+3) : o0;
            float b00 = Mp[o0+0];
            float b01 = (P>1)? Mp[o0+1] : 0.f;
            float b02 = (P>2)? Mp[o0+2] : 0.f;
            float b03 = (P>3)? Mp[o0+3] : 0.f;
            float b11 = (P>1)? Mp[o1+1] : 1.f;
            float b12 = (P>2)? Mp[o1+2] : 0.f;
            float b13 = (P>3)? Mp[o1+3] : 0.f;
            float b22 = (P>2)? Mp[o2+2] : 1.f;
            float b23 = (P>3)? Mp[o2+3] : 0.f;
            float b33 = (P>3)? Mp[o3+3] : 1.f;
            float i0 = 1.f/b00;
            float l10 = b01*i0, l20 = b02*i0, l30 = b03*i0;
            float c11 = b11 - l10*b01;
            float i1 = 1.f/c11;
            float c12 = b12 - l10*b02, c13 = b13 - l10*b03;
            float l21 = c12*i1, l31 = c13*i1;
            float c22 = b22 - l20*b02 - l21*c12;
            float i2 = 1.f/c22;
            float c23 = b23 - l20*b03 - l21*c13;
            float l32 = c23*i2;
            float c33 = b33 - l30*b03 - l31*c13 - l32*c23;
            float i3 = 1.f/c33;
            int C = tid << 2;
            float4 z = make_float4(0,0,0,0);
            float4 m0 = *(float4*)&Mp[o0 + C];
            float4 m1 = (P>1)? *(float4*)&Mp[o1 + C] : z;
            float4 m2 = (P>2)? *(float4*)&Mp[o2 + C] : z;
            float4 m3 = (P>3)? *(float4*)&Mp[o3 + C] : z;
            m1.x -= l10*m0.x; m1.y -= l10*m0.y; m1.z -= l10*m0.z; m1.w -= l10*m0.w;
            m2.x -= l20*m0.x + l21*m1.x; m2.y -= l20*m0.y + l21*m1.y;
            m2.z -= l20*m0.z + l21*m1.z; m2.w -= l20*m0.w + l21*m1.w;
            m3.x -= l30*m0.x + l31*m1.x + l32*m2.x;
            m3.y -= l30*m0.y + l31*m1.y + l32*m2.y;
            m3.z -= l30*m0.z + l31*m1.z + l32*m2.z;
            m3.w -= l30*m0.w + l31*m1.w + l32*m2.w;
            *(float4*)&Pr[0][C] = m0;
            *(float4*)&Pr[1][C] = m1;
            *(float4*)&Pr[2][C] = m2;
            *(float4*)&Pr[3][C] = m3;
            if (tid == 0) { invs[0]=i0; invs[1]=i1; invs[2]=i2; invs[3]=i3; }
        }
        __syncthreads();
        // phase B: rank-P update over CONTIGUOUS packed f4 chunks (all lanes busy)
        float iv0 = invs[0], iv1 = invs[1], iv2 = invs[2], iv3 = invs[3];
        int pkStart = rs_off(k0+1) >> 2;
        int pkTop = NPACK >> 2;
        int total = pkTop - pkStart;
        int len = (total + 255) >> 8;
        int pk = pkStart + tid * len;
        int pkEnd = pk + len; if (pkEnd > pkTop) pkEnd = pkTop;
        if (pk < pkTop) {
            int r = rowOf[pk];
            int rc = r - k0;
            float f0 = Pr[0][rc] * iv0;
            float f1 = (rc > 1) ? Pr[1][rc] * iv1 : 0.f;
            float f2 = (rc > 2) ? Pr[2][rc] * iv2 : 0.f;
            float f3 = (rc > 3) ? Pr[3][rc] * iv3 : 0.f;
            int roff = rs_off(r), rb = r & ~3;
            for (; pk < pkEnd; ++pk) {
                int r2 = rowOf[pk];
                if (r2 != r) {
                    r = r2; rc = r - k0;
                    f0 = Pr[0][rc] * iv0;
                    f1 = (rc > 1) ? Pr[1][rc] * iv1 : 0.f;
                    f2 = (rc > 2) ? Pr[2][rc] * iv2 : 0.f;
                    f3 = (rc > 3) ? Pr[3][rc] * iv3 : 0.f;
                    roff = rs_off(r); rb = r & ~3;
                }
                int C = (pk << 2) - roff + rb;
                int pc = C - k0;
                float4 v  = *(float4*)&Mp[pk << 2];
                float4 p0 = *(float4*)&Pr[0][pc];
                float4 p1 = *(float4*)&Pr[1][pc];
                float4 p2 = *(float4*)&Pr[2][pc];
                float4 p3 = *(float4*)&Pr[3][pc];
                v.x -= f0*p0.x + f1*p1.x + f2*p2.x + f3*p3.x;
                v.y -= f0*p0.y + f1*p1.y + f2*p2.y + f3*p3.y;
                v.z -= f0*p0.z + f1*p1.z + f2*p2.z + f3*p3.z;
                v.w -= f0*p0.w + f1*p1.w + f2*p2.w + f3*p3.w;
                *(float4*)&Mp[pk << 2] = v;
            }
        }
        __syncthreads();
    }
    // scale in place: diag slot = 1/d, cols>r (incl. RHS col 150 -> y) *= 1/d
    for (int r = tid; r < NS; r += 256)
        dvs[r] = rsqrtf(Mp[rs_off(r) + r - (r & ~3)]);
    __syncthreads();
    for (int idx = tid; idx < NS*LDW; idx += 256) {
        int r = idx / LDW, c = idx - r*LDW;
        int rbase = r & ~3;
        if (c < rbase) continue;
        int t = rs_off(r) + c - rbase;
        float dvr = dvs[r];
        if (c == r) Mp[t] = dvr;
        else if (c > r) Mp[t] *= dvr;
    }
    __syncthreads();
    // fused trsm: thread-per-test-column, u[] in registers, broadcast LDS rows.
    // u has LDW=152 entries: last f4 tail (t=148) writes u[150],u[151].
    if (tid < MS) {
        float tx = tscs[tid*3+0], ty = tscs[tid*3+1], tz = tscs[tid*3+2];
        float u[LDW];
        #pragma unroll
        for (int k = 0; k < NS; ++k) {
            float d0 = tx - scs[k*3+0];
            float d1 = ty - scs[k*3+1];
            float d2 = tz - scs[k*3+2];
            u[k] = expf(-((d0*d0 + d1*d1)*ill2 + d2*d2*ile2));
        }
        u[150] = 0.0f; u[151] = 0.0f;
        float qa = 0.0f, ra = 0.0f;
        #pragma unroll
        for (int k = 0; k < NS; ++k) {
            const int base = rs_off(k) - (k & ~3);
            float uk = u[k] * Mp[base + k];     // diag slot = 1/d
            qa += uk * uk;
            ra += uk * Mp[base + 150];          // scaled RHS = y_k
            const int kp = k + 1;
            const int ka = (kp + 3) & ~3;
            #pragma unroll
            for (int t = kp; t < ((ka < NS) ? ka : NS); ++t)
                u[t] -= Mp[base + t] * uk;
            #pragma unroll
            for (int t = ka; t < NS; t += 4) {
                float4 w = *(const float4*)&Mp[base + t];
                u[t+0] -= w.x * uk; u[t+1] -= w.y * uk;
                u[t+2] -= w.z * uk; u[t+3] -= w.w * uk;
            }
        }
        q[j*MS + tid] = qa;
        R[j*MS + tid] = ra;
    }
}

// K3: outputs. yPred[is][it] = sum_j A[it][j]*R[j][is];
//              yVar [is][it] = sig2 - sum_j A[it][j]^2 * q[j][is]
__global__ void finalize(const float* __restrict__ A, const float* __restrict__ q,
                         const float* __restrict__ R, const float* __restrict__ lsv,
                         float* __restrict__ out) {
    int idx = blockIdx.x * blockDim.x + threadIdx.x;
    if (idx >= MS * MT) return;
    int is = idx / MT, it = idx % MT;
    float sp = 0.0f, sv = 0.0f;
    for (int j = 0; j < NT; ++j) {
        float a = A[it*NT + j];
        sp += a * R[j*MS + is];
        sv += a*a * q[j*MS + is];
    }
    float sigv = expf(lsv[0]);
    out[idx] = sp;
    out[MS*MT + idx] = sigv - sv;
}

extern "C" void kernel_launch(void* const* d_in, const int* in_sizes, int n_in,
                              void* d_out, int out_size, void* d_ws, size_t ws_size,
                              hipStream_t stream) {
    const float* sc  = (const float*)d_in[0];   // 150x3
    const float* tc  = (const float*)d_in[1];   // 40x1
    const float* st  = (const float*)d_in[2];   // 150x40
    const float* tsc = (const float*)d_in[3];   // 200x3
    const float* ttc = (const float*)d_in[4];   // 30x1
    const float* lll = (const float*)d_in[5];
    const float* lle = (const float*)d_in[6];
    const float* llt = (const float*)d_in[7];
    const float* lnv = (const float*)d_in[8];
    const float* lsv = (const float*)d_in[9];
    float* out = (float*)d_out;

    float* ws   = (float*)d_ws;
    float* wt   = ws;                 // 40
    float* G    = wt   + 40;          // 6000
    float* Amat = G    + 6000;        // 1200
    float* q    = Amat + 1200;        // 8000
    float* R    = q    + 8000;        // 8000

    hipLaunchKernelGGL(jacobi_all, dim3(1), dim3(256), 0, stream,
                       tc, ttc, st, llt, wt, G, Amat);
    hipLaunchKernelGGL(chol_solve_all, dim3(NT), dim3(256), 0, stream,
                       sc, tsc, lll, lle, lnv, wt, G, q, R);
    hipLaunchKernelGGL(finalize, dim3((MS*MT + 255)/256), dim3(256), 0, stream,
                       Amat, q, R, lsv, out);
}

// Round 13
// 508.546 us; speedup vs baseline: 1.4884x; 1.4884x over previous
//
#include <hip/hip_runtime.h>
#include <math.h>

#define NS 150
#define LDW 152
#define NPACK 11848   // packed upper-tri floats (rows 16B-aligned)
#define NT 40
#define MS 200
#define MT 30
#define N_SWEEPS 6
#define ROUNDS (N_SWEEPS*(NT-1))
#define JITTER 0.1f

// ---- LDS union layout (bytes). Jacobi region overlaps Mp (sequential phases);
//      gv/Acol/wtj persist above everything the chol phase writes. ----
#define OFF_MP    0        // 47392
#define OFF_PR    47392    // 4*152*4 = 2432 -> 49824
#define OFF_INVS  49824    // 16 -> 49840
#define OFF_DVS   49840    // 600 -> 50440 (pad 50448)
#define OFF_SCS   50448    // 1800 -> 52248 (pad 52256)
#define OFF_TSCS  52256    // 2400 -> 54656
#define OFF_QV    54656    // 800 -> 55456
#define OFF_RV    55456    // 800 -> 56256
#define OFF_GV    56256    // 600 -> 56856
#define OFF_ACOL  56856    // 120 -> 56976
#define OFF_WTJ   56976    // 4  -> 56980
#define SMEM_BYTES 56992
// jacobi-phase (overlaps Mp region only):
#define OFF_A2    0        // 2*40*41*4 = 13120
#define OFF_VTS   13120    // 40*44*4 = 7040 -> 20160
#define OFF_PRM   20160    // 4*20*16 = 1280 -> 21440
#define OFF_TCS   21440    // 160 -> 21600   (all < OFF_PR and < OFF_GV)

// packed upper-tri storage: row r holds cols [r&~3, 152), 16B-aligned start.
__device__ __forceinline__ int rs_off(int r) {
    int g = r >> 2, rm = r & 3;
    return LDW * r - 8 * g * (g - 1) - 4 * rm * g;
}

__device__ __forceinline__ void jac_params(const float (*A)[NT+1], float4* dst,
                                           int i, int rr) {
    int i0 = i, i1 = NT - 1 - i;
    int p = (i0 == 0) ? 0 : ((i0 - 1 + rr) % (NT - 1)) + 1;
    int q = ((i1 - 1 + rr) % (NT - 1)) + 1;
    if (p > q) { int tsw = p; p = q; q = tsw; }
    float app = A[p][p], aqq = A[q][q], apq = A[p][q];
    float c, s;
    if (apq == 0.0f) { c = 1.0f; s = 0.0f; }
    else {
        float tau = (aqq - app) / (2.0f * apq);
        float tt = ((tau >= 0.0f) ? 1.0f : -1.0f) / (fabsf(tau) + sqrtf(1.0f + tau*tau));
        c = rsqrtf(1.0f + tt*tt);
        s = tt * c;
    }
    dst[i] = make_float4(c, s, __int_as_float(p), __int_as_float(q));
}

// ONE kernel, 40 independent blocks. Each block: redundant 40x40 Jacobi
// (R12-proven 1-barrier structure) -> extract wt_j, g_j, Acol_j -> build
// M_j = wtj*(S+JITTER*I)+nv*I packed in LDS (RHS g as col 150) -> rank-4
// panel factorization (R9-proven thread-per-row phase B) -> in-LDS scale ->
// fused trsm (200 cols, u[] in registers) -> atomicAdd rank-1 contribution
// into pre-zeroed out. No grid sync anywhere.
__global__ void __launch_bounds__(256, 1) gp_block(
        const float* __restrict__ sc,  const float* __restrict__ tc,
        const float* __restrict__ st,  const float* __restrict__ tsc,
        const float* __restrict__ ttc,
        const float* __restrict__ lll, const float* __restrict__ lle,
        const float* __restrict__ llt, const float* __restrict__ lnv,
        const float* __restrict__ lsv, float* __restrict__ out) {
    __shared__ __align__(16) char smem[SMEM_BYTES];
    int j = blockIdx.x, tid = threadIdx.x;

    // ---------- phase 1: Jacobi (redundant per block) ----------
    auto A2   = (float (*)[NT][NT+1])(smem + OFF_A2);
    auto Vts  = (float (*)[44])(smem + OFF_VTS);
    auto prm  = (float4 (*)[NT/2])(smem + OFF_PRM);
    float* tcs  = (float*)(smem + OFF_TCS);
    float* gv   = (float*)(smem + OFF_GV);
    float* Acol = (float*)(smem + OFF_ACOL);
    float* wtjs = (float*)(smem + OFF_WTJ);

    float ilt2 = expf(-2.0f * llt[0]);
    if (tid < NT) tcs[tid] = tc[tid];
    __syncthreads();
    for (int idx = tid; idx < NT*NT; idx += 256) {
        int i = idx / NT, jj = idx - i*NT;
        float dt = tcs[i] - tcs[jj];
        float v = expf(-dt*dt*ilt2);
        if (i == jj) v += JITTER;
        A2[0][i][jj] = v;
    }
    for (int idx = tid; idx < NT*44; idx += 256) {
        int jr = idx / 44, k = idx - jr*44;
        Vts[jr][k] = (jr == k) ? 1.0f : 0.0f;
    }
    __syncthreads();
    int wave = tid >> 6, lane = tid & 63;
    for (int rd = 0; rd < ROUNDS; ++rd) {
        int cur = rd & 1, nxt = cur ^ 1;
        float4* wp = prm[wave];
        if (lane < NT/2) jac_params(A2[cur], wp, lane, rd % (NT - 1));
        __builtin_amdgcn_wave_barrier();   // same-wave LDS in-order; pin compiler
        for (int t = tid; t < 600; t += 256) {
            if (t < 400) {
                int bi = t / 20, bj = t - bi*20;
                float4 Pi = wp[bi], Pj = wp[bj];
                int pi = __float_as_int(Pi.z), qi = __float_as_int(Pi.w);
                int pj = __float_as_int(Pj.z), qj = __float_as_int(Pj.w);
                float ci = Pi.x, si = Pi.y, cj = Pj.x, sj = Pj.y;
                float a00 = A2[cur][pi][pj], a01 = A2[cur][pi][qj];
                float a10 = A2[cur][qi][pj], a11 = A2[cur][qi][qj];
                float b00 = ci*a00 - si*a10, b01 = ci*a01 - si*a11;
                float b10 = si*a00 + ci*a10, b11 = si*a01 + ci*a11;
                A2[nxt][pi][pj] = cj*b00 - sj*b01; A2[nxt][pi][qj] = sj*b00 + cj*b01;
                A2[nxt][qi][pj] = cj*b10 - sj*b11; A2[nxt][qi][qj] = sj*b10 + cj*b11;
            } else {
                int u2 = t - 400;
                int pr = u2 / 10, ch = (u2 - pr*10) << 2;
                float4 P = wp[pr];
                int pj = __float_as_int(P.z), qj = __float_as_int(P.w);
                float c = P.x, s = P.y;
                float4 vp = *(float4*)&Vts[pj][ch];
                float4 vq = *(float4*)&Vts[qj][ch];
                float4 np, nq;
                np.x = c*vp.x - s*vq.x; nq.x = s*vp.x + c*vq.x;
                np.y = c*vp.y - s*vq.y; nq.y = s*vp.y + c*vq.y;
                np.z = c*vp.z - s*vq.z; nq.z = s*vp.z + c*vq.z;
                np.w = c*vp.w - s*vq.w; nq.w = s*vp.w + c*vq.w;
                *(float4*)&Vts[pj][ch] = np;
                *(float4*)&Vts[qj][ch] = nq;
            }
        }
        __syncthreads();
    }
    const int fin = ROUNDS & 1;
    // ---------- extraction: only column j is needed by this block ----------
    if (tid == 0) wtjs[0] = A2[fin][j][j];
    for (int s = tid; s < NS; s += 256) {
        const float4* va = (const float4*)&Vts[j][0];
        const float4* sa = (const float4*)&st[s*NT];
        float acc = 0.0f;
        #pragma unroll
        for (int c4 = 0; c4 < NT/4; ++c4) {
            float4 a = va[c4], b = sa[c4];
            acc += a.x*b.x + a.y*b.y + a.z*b.z + a.w*b.w;
        }
        gv[s] = acc;
    }
    if (tid < MT) {
        float ttv = ttc[tid];
        float acc = 0.0f;
        for (int t = 0; t < NT; ++t) {
            float dt = ttv - tcs[t];
            acc += expf(-dt*dt*ilt2) * Vts[j][t];
        }
        Acol[tid] = acc;
    }
    __syncthreads();

    // ---------- phase 2: chol + trsm (R9-proven) ----------
    float* Mp   = (float*)(smem + OFF_MP);
    auto   Pr   = (float (*)[LDW])(smem + OFF_PR);
    float* invs = (float*)(smem + OFF_INVS);
    float* dvs  = (float*)(smem + OFF_DVS);
    float* scs  = (float*)(smem + OFF_SCS);
    float* tscs = (float*)(smem + OFF_TSCS);
    float* qv   = (float*)(smem + OFF_QV);
    float* Rv   = (float*)(smem + OFF_RV);
    float wtj = wtjs[0];
    float nv = expf(lnv[0]);
    float ill2 = expf(-2.0f * lll[0]);
    float ile2 = expf(-2.0f * lle[0]);
    for (int t = tid; t < NS*3; t += 256) scs[t] = sc[t];
    for (int t = tid; t < MS*3; t += 256) tscs[t] = tsc[t];
    __syncthreads();
    for (int idx = tid; idx < NS*LDW; idx += 256) {
        int r = idx / LDW, c = idx - r*LDW;
        int rbase = r & ~3;
        if (c < rbase) continue;
        float v;
        if (c < NS) {
            float d0 = scs[r*3+0] - scs[c*3+0];
            float d1 = scs[r*3+1] - scs[c*3+1];
            float d2 = scs[r*3+2] - scs[c*3+2];
            v = wtj * expf(-((d0*d0 + d1*d1)*ill2 + d2*d2*ile2));
            if (c == r) v += wtj * JITTER + nv;   // spatial jitter rides wtj
        } else if (c == NS) {
            v = gv[r];
        } else {
            v = 0.0f;
        }
        Mp[rs_off(r) + c - rbase] = v;
    }
    __syncthreads();
    for (int k0 = 0; k0 < NS - 1; k0 += 4) {
        int P = NS - k0; if (P > 4) P = 4;
        int W4 = (LDW - k0) >> 2;
        // phase A: stage + pre-eliminate panel rows into Pr (single wave)
        if (tid < W4) {
            int o0 = rs_off(k0);
            int o1 = (P > 1) ? rs_off(k0+1) : o0;
            int o2 = (P > 2) ? rs_off(k0+2) : o0;
            int o3 = (P > 3) ? rs_off(k0+3) : o0;
            float b00 = Mp[o0+0];
            float b01 = (P>1)? Mp[o0+1] : 0.f;
            float b02 = (P>2)? Mp[o0+2] : 0.f;
            float b03 = (P>3)? Mp[o0+3] : 0.f;
            float b11 = (P>1)? Mp[o1+1] : 1.f;
            float b12 = (P>2)? Mp[o1+2] : 0.f;
            float b13 = (P>3)? Mp[o1+3] : 0.f;
            float b22 = (P>2)? Mp[o2+2] : 1.f;
            float b23 = (P>3)? Mp[o2+3] : 0.f;
            float b33 = (P>3)? Mp[o3+3] : 1.f;
            float i0 = 1.f/b00;
            float l10 = b01*i0, l20 = b02*i0, l30 = b03*i0;
            float c11 = b11 - l10*b01;
            float i1 = 1.f/c11;
            float c12 = b12 - l10*b02, c13 = b13 - l10*b03;
            float l21 = c12*i1, l31 = c13*i1;
            float c22 = b22 - l20*b02 - l21*c12;
            float i2 = 1.f/c22;
            float c23 = b23 - l20*b03 - l21*c13;
            float l32 = c23*i2;
            float c33 = b33 - l30*b03 - l31*c13 - l32*c23;
            float i3 = 1.f/c33;
            int C = tid << 2;
            float4 z = make_float4(0,0,0,0);
            float4 m0 = *(float4*)&Mp[o0 + C];
            float4 m1 = (P>1)? *(float4*)&Mp[o1 + C] : z;
            float4 m2 = (P>2)? *(float4*)&Mp[o2 + C] : z;
            float4 m3 = (P>3)? *(float4*)&Mp[o3 + C] : z;
            m1.x -= l10*m0.x; m1.y -= l10*m0.y; m1.z -= l10*m0.z; m1.w -= l10*m0.w;
            m2.x -= l20*m0.x + l21*m1.x; m2.y -= l20*m0.y + l21*m1.y;
            m2.z -= l20*m0.z + l21*m1.z; m2.w -= l20*m0.w + l21*m1.w;
            m3.x -= l30*m0.x + l31*m1.x + l32*m2.x;
            m3.y -= l30*m0.y + l31*m1.y + l32*m2.y;
            m3.z -= l30*m0.z + l31*m1.z + l32*m2.z;
            m3.w -= l30*m0.w + l31*m1.w + l32*m2.w;
            *(float4*)&Pr[0][C] = m0;
            *(float4*)&Pr[1][C] = m1;
            *(float4*)&Pr[2][C] = m2;
            *(float4*)&Pr[3][C] = m3;
            if (tid == 0) { invs[0]=i0; invs[1]=i1; invs[2]=i2; invs[3]=i3; }
        }
        __syncthreads();
        // phase B (R9-proven): thread-per-row, contiguous f4 column sweep
        float iv0 = invs[0], iv1 = invs[1], iv2 = invs[2], iv3 = invs[3];
        for (int r = k0 + 1 + tid; r < NS; r += 256) {
            int rc = r - k0;
            int E = rc < P ? rc : P;
            float f0 = Pr[0][rc] * iv0;
            float f1 = (E > 1) ? Pr[1][rc] * iv1 : 0.f;
            float f2 = (E > 2) ? Pr[2][rc] * iv2 : 0.f;
            float f3 = (E > 3) ? Pr[3][rc] * iv3 : 0.f;
            int rbase = r & ~3;
            int ro = rs_off(r) - rbase;
            for (int C = rbase; C < LDW; C += 4) {
                int pc = C - k0;
                float4 v  = *(float4*)&Mp[ro + C];
                float4 p0 = *(float4*)&Pr[0][pc];
                float4 p1 = *(float4*)&Pr[1][pc];
                float4 p2 = *(float4*)&Pr[2][pc];
                float4 p3 = *(float4*)&Pr[3][pc];
                v.x -= f0*p0.x + f1*p1.x + f2*p2.x + f3*p3.x;
                v.y -= f0*p0.y + f1*p1.y + f2*p2.y + f3*p3.y;
                v.z -= f0*p0.z + f1*p1.z + f2*p2.z + f3*p3.z;
                v.w -= f0*p0.w + f1*p1.w + f2*p2.w + f3*p3.w;
                *(float4*)&Mp[ro + C] = v;
            }
        }
        __syncthreads();
    }
    // scale in place: diag slot = 1/d, cols>r (incl. RHS col 150 -> y) *= 1/d
    for (int r = tid; r < NS; r += 256)
        dvs[r] = rsqrtf(Mp[rs_off(r) + r - (r & ~3)]);
    __syncthreads();
    for (int idx = tid; idx < NS*LDW; idx += 256) {
        int r = idx / LDW, c = idx - r*LDW;
        int rbase = r & ~3;
        if (c < rbase) continue;
        int t = rs_off(r) + c - rbase;
        float dvr = dvs[r];
        if (c == r) Mp[t] = dvr;
        else if (c > r) Mp[t] *= dvr;
    }
    __syncthreads();
    // fused trsm: thread-per-test-column, u[] in registers (152 w/ zero tail)
    if (tid < MS) {
        float tx = tscs[tid*3+0], ty = tscs[tid*3+1], tz = tscs[tid*3+2];
        float u[LDW];
        #pragma unroll
        for (int k = 0; k < NS; ++k) {
            float d0 = tx - scs[k*3+0];
            float d1 = ty - scs[k*3+1];
            float d2 = tz - scs[k*3+2];
            u[k] = expf(-((d0*d0 + d1*d1)*ill2 + d2*d2*ile2));
        }
        u[150] = 0.0f; u[151] = 0.0f;
        float qa = 0.0f, ra = 0.0f;
        #pragma unroll
        for (int k = 0; k < NS; ++k) {
            const int base = rs_off(k) - (k & ~3);
            float uk = u[k] * Mp[base + k];     // diag slot = 1/d
            qa += uk * uk;
            ra += uk * Mp[base + 150];          // scaled RHS = y_k
            const int kp = k + 1;
            const int ka = (kp + 3) & ~3;
            #pragma unroll
            for (int t = kp; t < ((ka < NS) ? ka : NS); ++t)
                u[t] -= Mp[base + t] * uk;
            #pragma unroll
            for (int t = ka; t < NS; t += 4) {
                float4 w = *(const float4*)&Mp[base + t];
                u[t+0] -= w.x * uk; u[t+1] -= w.y * uk;
                u[t+2] -= w.z * uk; u[t+3] -= w.w * uk;
            }
        }
        qv[tid] = qa;
        Rv[tid] = ra;
    }
    __syncthreads();

    // ---------- phase 3: atomic rank-1 accumulation into out ----------
    float sigv = expf(lsv[0]);
    for (int idx = tid; idx < MS*MT; idx += 256) {
        int is = idx / MT, it = idx - is*MT;
        float a = Acol[it];
        atomicAdd(&out[idx], a * Rv[is]);
        float c2 = -a * a * qv[is];
        if (j == 0) c2 += sigv;
        atomicAdd(&out[MS*MT + idx], c2);
    }
}

extern "C" void kernel_launch(void* const* d_in, const int* in_sizes, int n_in,
                              void* d_out, int out_size, void* d_ws, size_t ws_size,
                              hipStream_t stream) {
    const float* sc  = (const float*)d_in[0];   // 150x3
    const float* tc  = (const float*)d_in[1];   // 40x1
    const float* st  = (const float*)d_in[2];   // 150x40
    const float* tsc = (const float*)d_in[3];   // 200x3
    const float* ttc = (const float*)d_in[4];   // 30x1
    const float* lll = (const float*)d_in[5];
    const float* lle = (const float*)d_in[6];
    const float* llt = (const float*)d_in[7];
    const float* lnv = (const float*)d_in[8];
    const float* lsv = (const float*)d_in[9];
    float* out = (float*)d_out;

    // out starts poisoned each timed launch; zero it (capture-legal async op)
    hipMemsetAsync(out, 0, (size_t)out_size * sizeof(float), stream);
    hipLaunchKernelGGL(gp_block, dim3(NT), dim3(256), 0, stream,
                       sc, tc, st, tsc, ttc, lll, lle, llt, lnv, lsv, out);
}

// Round 14
// 418.425 us; speedup vs baseline: 1.8089x; 1.2154x over previous
//
#include <hip/hip_runtime.h>
#include <math.h>

#define NS 150
#define LDW 152
#define NPACK 11848   // packed upper-tri floats (rows 16B-aligned)
#define NT 40
#define MS 200
#define MT 30
#define N_SWEEPS 6
#define ROUNDS (N_SWEEPS*(NT-1))
#define JITTER 0.1f
#define NTHR 512

// ---- LDS union layout (bytes) ----
#define OFF_MP    0        // 47392
#define OFF_PR    47392    // 8*152*4 = 4864 -> 52256
#define OFF_INVS  52256    // 32 -> 52288
#define OFF_DVS   52288    // 600 -> 52896 (pad)
#define OFF_SCS   52896    // 1800 -> 54704 (pad)
#define OFF_TSCS  54704    // 2400 -> 57104
#define OFF_QV    57104    // 800 -> 57904
#define OFF_RV    57904    // 800 -> 58704
#define OFF_GV    58704    // 600 -> 59304
#define OFF_ACOL  59304    // 120 -> 59424
#define OFF_WTJ   59424    // 4  -> 59428
#define SMEM_BYTES 59440
// jacobi-phase overlay (inside Mp region only):
#define OFF_A2    0        // 2*40*41*4 = 13120
#define OFF_VTS   13120    // 40*44*4 = 7040 -> 20160
#define OFF_PRM   20160    // 8*20*16 = 2560 -> 22720
#define OFF_TCS   22720    // 160 -> 22880   (< OFF_PR; gv/Acol/wtj live above)

// packed upper-tri storage: row r holds cols [r&~3, 152), 16B-aligned start.
__device__ __forceinline__ int rs_off(int r) {
    int g = r >> 2, rm = r & 3;
    return LDW * r - 8 * g * (g - 1) - 4 * rm * g;
}

__device__ __forceinline__ void jac_params(const float (*A)[NT+1], float4* dst,
                                           int i, int rr) {
    int i0 = i, i1 = NT - 1 - i;
    int p = (i0 == 0) ? 0 : ((i0 - 1 + rr) % (NT - 1)) + 1;
    int q = ((i1 - 1 + rr) % (NT - 1)) + 1;
    if (p > q) { int tsw = p; p = q; q = tsw; }
    float app = A[p][p], aqq = A[q][q], apq = A[p][q];
    float c, s;
    if (apq == 0.0f) { c = 1.0f; s = 0.0f; }
    else {
        float tau = (aqq - app) / (2.0f * apq);
        float tt = ((tau >= 0.0f) ? 1.0f : -1.0f) / (fabsf(tau) + sqrtf(1.0f + tau*tau));
        c = rsqrtf(1.0f + tt*tt);
        s = tt * c;
    }
    dst[i] = make_float4(c, s, __int_as_float(p), __int_as_float(q));
}

// ONE kernel, 40 blocks x 512 threads. Per block: redundant Jacobi -> extract
// (wt_j, g_j, Acol_j) -> packed M_j build -> rank-8 panel factorization ->
// in-LDS scale -> fused trsm -> atomicAdd rank-1 epilogue into zeroed out.
__global__ void __launch_bounds__(NTHR, 1) gp_block(
        const float* __restrict__ sc,  const float* __restrict__ tc,
        const float* __restrict__ st,  const float* __restrict__ tsc,
        const float* __restrict__ ttc,
        const float* __restrict__ lll, const float* __restrict__ lle,
        const float* __restrict__ llt, const float* __restrict__ lnv,
        const float* __restrict__ lsv, float* __restrict__ out) {
    __shared__ __align__(16) char smem[SMEM_BYTES];
    int j = blockIdx.x, tid = threadIdx.x;

    auto A2   = (float (*)[NT][NT+1])(smem + OFF_A2);
    auto Vts  = (float (*)[44])(smem + OFF_VTS);
    auto prm  = (float4 (*)[NT/2])(smem + OFF_PRM);
    float* tcs  = (float*)(smem + OFF_TCS);
    float* gv   = (float*)(smem + OFF_GV);
    float* Acol = (float*)(smem + OFF_ACOL);
    float* wtjs = (float*)(smem + OFF_WTJ);
    float* scs  = (float*)(smem + OFF_SCS);
    float* tscs = (float*)(smem + OFF_TSCS);

    float ilt2 = expf(-2.0f * llt[0]);
    if (tid < NT) tcs[tid] = tc[tid];
    // hoist coord staging (disjoint LDS; latency hides under Jacobi)
    for (int t = tid; t < NS*3; t += NTHR) scs[t] = sc[t];
    for (int t = tid; t < MS*3; t += NTHR) tscs[t] = tsc[t];
    __syncthreads();
    for (int idx = tid; idx < NT*NT; idx += NTHR) {
        int i = idx / NT, jj = idx - i*NT;
        float dt = tcs[i] - tcs[jj];
        float v = expf(-dt*dt*ilt2);
        if (i == jj) v += JITTER;
        A2[0][i][jj] = v;
    }
    for (int idx = tid; idx < NT*44; idx += NTHR) {
        int jr = idx / 44, k = idx - jr*44;
        Vts[jr][k] = (jr == k) ? 1.0f : 0.0f;
    }
    __syncthreads();
    int wave = tid >> 6, lane = tid & 63;
    for (int rd = 0; rd < ROUNDS; ++rd) {
        int cur = rd & 1, nxt = cur ^ 1;
        float4* wp = prm[wave];
        if (lane < NT/2) jac_params(A2[cur], wp, lane, rd % (NT - 1));
        __builtin_amdgcn_wave_barrier();   // same-wave LDS in-order; pin compiler
        for (int t = tid; t < 600; t += NTHR) {
            if (t < 400) {
                int bi = t / 20, bj = t - bi*20;
                float4 Pi = wp[bi], Pj = wp[bj];
                int pi = __float_as_int(Pi.z), qi = __float_as_int(Pi.w);
                int pj = __float_as_int(Pj.z), qj = __float_as_int(Pj.w);
                float ci = Pi.x, si = Pi.y, cj = Pj.x, sj = Pj.y;
                float a00 = A2[cur][pi][pj], a01 = A2[cur][pi][qj];
                float a10 = A2[cur][qi][pj], a11 = A2[cur][qi][qj];
                float b00 = ci*a00 - si*a10, b01 = ci*a01 - si*a11;
                float b10 = si*a00 + ci*a10, b11 = si*a01 + ci*a11;
                A2[nxt][pi][pj] = cj*b00 - sj*b01; A2[nxt][pi][qj] = sj*b00 + cj*b01;
                A2[nxt][qi][pj] = cj*b10 - sj*b11; A2[nxt][qi][qj] = sj*b10 + cj*b11;
            } else {
                int u2 = t - 400;
                int pr = u2 / 10, ch = (u2 - pr*10) << 2;
                float4 P = wp[pr];
                int pj = __float_as_int(P.z), qj = __float_as_int(P.w);
                float c = P.x, s = P.y;
                float4 vp = *(float4*)&Vts[pj][ch];
                float4 vq = *(float4*)&Vts[qj][ch];
                float4 np, nq;
                np.x = c*vp.x - s*vq.x; nq.x = s*vp.x + c*vq.x;
                np.y = c*vp.y - s*vq.y; nq.y = s*vp.y + c*vq.y;
                np.z = c*vp.z - s*vq.z; nq.z = s*vp.z + c*vq.z;
                np.w = c*vp.w - s*vq.w; nq.w = s*vp.w + c*vq.w;
                *(float4*)&Vts[pj][ch] = np;
                *(float4*)&Vts[qj][ch] = nq;
            }
        }
        __syncthreads();
    }
    const int fin = ROUNDS & 1;
    if (tid == 0) wtjs[0] = A2[fin][j][j];
    for (int s = tid; s < NS; s += NTHR) {
        const float4* va = (const float4*)&Vts[j][0];
        const float4* sa = (const float4*)&st[s*NT];
        float acc = 0.0f;
        #pragma unroll
        for (int c4 = 0; c4 < NT/4; ++c4) {
            float4 a = va[c4], b = sa[c4];
            acc += a.x*b.x + a.y*b.y + a.z*b.z + a.w*b.w;
        }
        gv[s] = acc;
    }
    if (tid < MT) {
        float ttv = ttc[tid];
        float acc = 0.0f;
        for (int t = 0; t < NT; ++t) {
            float dt = ttv - tcs[t];
            acc += expf(-dt*dt*ilt2) * Vts[j][t];
        }
        Acol[tid] = acc;
    }
    __syncthreads();

    // ---------- phase 2: build + rank-8 factor + scale + trsm ----------
    float* Mp   = (float*)(smem + OFF_MP);
    auto   Pr   = (float (*)[LDW])(smem + OFF_PR);
    float* invs = (float*)(smem + OFF_INVS);
    float* dvs  = (float*)(smem + OFF_DVS);
    float* qv   = (float*)(smem + OFF_QV);
    float* Rv   = (float*)(smem + OFF_RV);
    float wtj = wtjs[0];
    float nv = expf(lnv[0]);
    float ill2 = expf(-2.0f * lll[0]);
    float ile2 = expf(-2.0f * lle[0]);
    for (int idx = tid; idx < NS*LDW; idx += NTHR) {
        int r = idx / LDW, c = idx - r*LDW;
        int rbase = r & ~3;
        if (c < rbase) continue;
        float v;
        if (c < NS) {
            float d0 = scs[r*3+0] - scs[c*3+0];
            float d1 = scs[r*3+1] - scs[c*3+1];
            float d2 = scs[r*3+2] - scs[c*3+2];
            v = wtj * expf(-((d0*d0 + d1*d1)*ill2 + d2*d2*ile2));
            if (c == r) v += wtj * JITTER + nv;   // spatial jitter rides wtj
        } else if (c == NS) {
            v = gv[r];
        } else {
            v = 0.0f;
        }
        Mp[rs_off(r) + c - rbase] = v;
    }
    __syncthreads();
    for (int k0 = 0; k0 < NS - 1; k0 += 8) {
        int P = NS - k0; if (P > 8) P = 8;
        int W4 = (LDW - k0) >> 2;
        // phase A (single wave): redundant 8x8 elimination + chunk pre-elim -> Pr
        if (tid < W4) {
            int off[8];
            #pragma unroll
            for (int i = 0; i < 8; ++i)
                off[i] = (i < P) ? (rs_off(k0 + i) - ((i >= 4) ? 4 : 0)) : 0;
            float Bm[8][8];
            #pragma unroll
            for (int i = 0; i < 8; ++i) {
                #pragma unroll
                for (int c = 0; c < 8; ++c)
                    Bm[i][c] = (i < P && c >= i) ? Mp[off[i] + c]
                                                 : ((c == i) ? 1.0f : 0.0f);
            }
            float Lf[8][8]; float iv[8];
            #pragma unroll
            for (int k = 0; k < 8; ++k) {
                iv[k] = 1.0f / Bm[k][k];
                #pragma unroll
                for (int i = k + 1; i < 8; ++i) {
                    float l = Bm[k][i] * iv[k];
                    Lf[i][k] = l;
                    #pragma unroll
                    for (int c = i; c < 8; ++c) Bm[i][c] -= l * Bm[k][c];
                }
            }
            if (tid == 0) {
                #pragma unroll
                for (int i = 0; i < 8; ++i) invs[i] = iv[i];
            }
            int C = tid << 2;
            float4 m[8];
            #pragma unroll
            for (int i = 0; i < 8; ++i) {
                bool ok = (i < P) && (i < 4 || C >= 4);
                m[i] = ok ? *(float4*)&Mp[off[i] + C] : make_float4(0,0,0,0);
            }
            #pragma unroll
            for (int i = 1; i < 8; ++i) {
                #pragma unroll
                for (int k = 0; k < i; ++k) {
                    float l = Lf[i][k];
                    m[i].x -= l*m[k].x; m[i].y -= l*m[k].y;
                    m[i].z -= l*m[k].z; m[i].w -= l*m[k].w;
                }
            }
            #pragma unroll
            for (int i = 0; i < 8; ++i) *(float4*)&Pr[i][C] = m[i];
        }
        __syncthreads();
        // phase B: rank-8 trailing update, thread-per-row, contiguous f4 sweep
        for (int r = k0 + 1 + tid; r < NS; r += NTHR) {
            int rc = r - k0;
            float f[8];
            #pragma unroll
            for (int i = 0; i < 8; ++i)
                f[i] = (rc > i && i < P) ? Pr[i][rc] * invs[i] : 0.0f;
            int rbase = r & ~3;
            int ro = rs_off(r) - rbase;
            for (int C = rbase; C < LDW; C += 4) {
                int pc = C - k0;
                float4 v = *(float4*)&Mp[ro + C];
                #pragma unroll
                for (int i = 0; i < 8; ++i) {
                    float4 p = *(float4*)&Pr[i][pc];
                    v.x -= f[i]*p.x; v.y -= f[i]*p.y;
                    v.z -= f[i]*p.z; v.w -= f[i]*p.w;
                }
                *(float4*)&Mp[ro + C] = v;
            }
        }
        __syncthreads();
    }
    // scale in place: diag slot = 1/d, cols>r (incl. RHS col 150 -> y) *= 1/d
    for (int r = tid; r < NS; r += NTHR)
        dvs[r] = rsqrtf(Mp[rs_off(r) + r - (r & ~3)]);
    __syncthreads();
    for (int idx = tid; idx < NS*LDW; idx += NTHR) {
        int r = idx / LDW, c = idx - r*LDW;
        int rbase = r & ~3;
        if (c < rbase) continue;
        int t = rs_off(r) + c - rbase;
        float dvr = dvs[r];
        if (c == r) Mp[t] = dvr;
        else if (c > r) Mp[t] *= dvr;
    }
    __syncthreads();
    // fused trsm: thread-per-test-column, u[] in registers (152 w/ zero tail)
    if (tid < MS) {
        float tx = tscs[tid*3+0], ty = tscs[tid*3+1], tz = tscs[tid*3+2];
        float u[LDW];
        #pragma unroll
        for (int k = 0; k < NS; ++k) {
            float d0 = tx - scs[k*3+0];
            float d1 = ty - scs[k*3+1];
            float d2 = tz - scs[k*3+2];
            u[k] = expf(-((d0*d0 + d1*d1)*ill2 + d2*d2*ile2));
        }
        u[150] = 0.0f; u[151] = 0.0f;
        float qa = 0.0f, ra = 0.0f;
        #pragma unroll
        for (int k = 0; k < NS; ++k) {
            const int base = rs_off(k) - (k & ~3);
            float uk = u[k] * Mp[base + k];     // diag slot = 1/d
            qa += uk * uk;
            ra += uk * Mp[base + 150];          // scaled RHS = y_k
            const int kp = k + 1;
            const int ka = (kp + 3) & ~3;
            #pragma unroll
            for (int t = kp; t < ((ka < NS) ? ka : NS); ++t)
                u[t] -= Mp[base + t] * uk;
            #pragma unroll
            for (int t = ka; t < NS; t += 4) {
                float4 w = *(const float4*)&Mp[base + t];
                u[t+0] -= w.x * uk; u[t+1] -= w.y * uk;
                u[t+2] -= w.z * uk; u[t+3] -= w.w * uk;
            }
        }
        qv[tid] = qa;
        Rv[tid] = ra;
    }
    __syncthreads();

    // ---------- phase 3: atomic rank-1 accumulation into out ----------
    float sigv = expf(lsv[0]);
    for (int idx = tid; idx < MS*MT; idx += NTHR) {
        int is = idx / MT, it = idx - is*MT;
        float a = Acol[it];
        atomicAdd(&out[idx], a * Rv[is]);
        float c2 = -a * a * qv[is];
        if (j == 0) c2 += sigv;
        atomicAdd(&out[MS*MT + idx], c2);
    }
}

extern "C" void kernel_launch(void* const* d_in, const int* in_sizes, int n_in,
                              void* d_out, int out_size, void* d_ws, size_t ws_size,
                              hipStream_t stream) {
    const float* sc  = (const float*)d_in[0];   // 150x3
    const float* tc  = (const float*)d_in[1];   // 40x1
    const float* st  = (const float*)d_in[2];   // 150x40
    const float* tsc = (const float*)d_in[3];   // 200x3
    const float* ttc = (const float*)d_in[4];   // 30x1
    const float* lll = (const float*)d_in[5];
    const float* lle = (const float*)d_in[6];
    const float* llt = (const float*)d_in[7];
    const float* lnv = (const float*)d_in[8];
    const float* lsv = (const float*)d_in[9];
    float* out = (float*)d_out;

    hipMemsetAsync(out, 0, (size_t)out_size * sizeof(float), stream);
    hipLaunchKernelGGL(gp_block, dim3(NT), dim3(NTHR), 0, stream,
                       sc, tc, st, tsc, ttc, lll, lle, llt, lnv, lsv, out);
}